// Round 2
// baseline (916.079 us; speedup 1.0000x reference)
//
#include <hip/hip_runtime.h>
#include <stdint.h>

using u8  = unsigned char;
using u16 = unsigned short;
using u32 = unsigned int;

typedef __bf16 bf16x8 __attribute__((ext_vector_type(8)));
typedef float  f32x4  __attribute__((ext_vector_type(4)));
typedef u16    u16x8  __attribute__((ext_vector_type(8)));

__device__ __forceinline__ float b2f(u16 u) {
    union { u32 i; float f; } v; v.i = ((u32)u) << 16; return v.f;
}
__device__ __forceinline__ u16 f2bf(float f) {
    union { float f; u32 i; } v; v.f = f;
    u32 u = v.i;
    return (u16)((u + 0x7FFFu + ((u >> 16) & 1u)) >> 16);
}

// ws layout (u16 elements, relative to wsW = (u16*)d_ws + WS_OFF):
//   [OFF_W1..] masked zero-padded bf16 weights
//   [OFF_XC ] bf16 copy of x          32768x1024
//   [OFF_H1C] bf16 h1 + 64 guard      32768x1000
//   [OFF_H2C] bf16 h2 + 64 guard      32768x800
//   [OFF_H3C] bf16 h3 + 64 guard      32768x400
//   [OFF_H5S] f32 h5 atomic scratch   32768x6 (zeroed by prep)
#define WS_OFF 256
#define OFF_W1 0
#define OFF_W2 1048576
#define OFF_W3 1966080
#define OFF_W4 2392064
#define PS1 1048576
#define PS2 917504
#define PS3 425984
#define PS4 286720
#define TOTW 2678784
#define GUARD 64
#define OFF_XC  2678784
#define OFF_H1C 36233216
#define OFF_H2C 69001280
#define OFF_H3C 95215744
#define OFF_H5S 108323008
#define H5N 196608        // 32768*6 f32 scratch elements
#define XCONV_N 4194304   // 32768*1024/8

// ---------------- dtype / mask-width detection -----------------------------
__global__ void detect_kernel(int* __restrict__ flags,
                              const u32* __restrict__ xw,
                              const u32* __restrict__ mw) {
    const int lane = threadIdx.x;   // 64 threads
    int outl = 0;
#pragma unroll
    for (int i = 0; i < 4; ++i) {
        u32 u = xw[lane * 4 + i];
        u32 e = (u >> 7) & 0xFFu;              // exponent field of LOW u16 as bf16
        if (e < 90u || e > 140u) outl++;       // bf16 world: ~0 ; f32 world: ~80%
    }
#pragma unroll
    for (int off = 32; off; off >>= 1) outl += __shfl_down(outl, off, 64);

    u32 v0 = mw[lane], v1 = mw[64 + lane];
    bool w4 = (v0 == 0u || v0 == 1u || v0 == 0x3F800000u) &&
              (v1 == 0u || v1 == 1u || v1 == 0x3F800000u);
    auto okh = [](u32 h) { return h == 0u || h == 1u || h == 0x3F80u; };
    bool w2 = okh(v0 & 0xFFFFu) && okh(v0 >> 16) && okh(v1 & 0xFFFFu) && okh(v1 >> 16);
    int all4 = __all(w4 ? 1 : 0);
    int all2 = __all(w2 ? 1 : 0);
    if (lane == 0) {
        flags[0] = (outl > 64) ? 1 : 0;
        flags[1] = all4 ? 0 : (all2 ? 1 : 2);
    }
}

__device__ __forceinline__ bool readM(const void* m, int s, int mwid) {
    if (mwid == 0) return ((const u32*)m)[s] != 0u;
    if (mwid == 1) return ((const u16*)m)[s] != 0u;
    return ((const u8*)m)[s] != 0u;
}
__device__ __forceinline__ u16 readW(const void* W, int s, int dt) {
    if (dt) return f2bf(((const float*)W)[s]);
    return ((const u16*)W)[s];
}

// ------ weight prep + guards + h5-scratch zero + (mode 1) x -> bf16 --------
__global__ void prep_weights(const int* __restrict__ flags, u16* __restrict__ ws,
                             const void* __restrict__ W1, const void* __restrict__ m1,
                             const void* __restrict__ W2, const void* __restrict__ m2,
                             const void* __restrict__ W3, const void* __restrict__ m3,
                             const void* __restrict__ W4, const void* __restrict__ m4,
                             const void* __restrict__ xv)
{
    const int dt = flags[0], mwid = flags[1];
    int idx = blockIdx.x * 256 + threadIdx.x;
    if (idx < PS1) {
        int n = idx >> 10, k = idx & 1023;
        u16 v = 0;
        if (n < 1000) { int s = n * 1024 + k; if (readM(m1, s, mwid)) v = readW(W1, s, dt); }
        ws[idx] = v;
    } else if (idx < PS1 + PS2) {
        int j = idx - PS1; int n = j >> 10, k = j & 1023;
        u16 v = 0;
        if (n < 800 && k < 1000) { int s = n * 1000 + k; if (readM(m2, s, mwid)) v = readW(W2, s, dt); }
        ws[idx] = v;
    } else if (idx < PS1 + PS2 + PS3) {
        int j = idx - (PS1 + PS2); int n = j / 832, k = j - n * 832;
        u16 v = 0;
        if (n < 400 && k < 800) { int s = n * 800 + k; if (readM(m3, s, mwid)) v = readW(W3, s, dt); }
        ws[idx] = v;
    } else if (idx < TOTW) {
        int j = idx - (PS1 + PS2 + PS3); int n = j / 448, k = j - n * 448;
        u16 v = 0;
        if (n < 600 && k < 400) { int s = n * 400 + k; if (readM(m4, s, mwid)) v = readW(W4, s, dt); }
        ws[idx] = v;
    } else if (idx < TOTW + 3 * GUARD) {
        // zero guard bands after h1c/h2c/h3c (K-pad overrun of the LAST row
        // must read finite values; workspace poison may be NaN-patterned)
        int g = idx - TOTW;
        int zone = g >> 6;
        size_t off = (zone == 0) ? ((size_t)OFF_H1C + 32768000)
                   : (zone == 1) ? ((size_t)OFF_H2C + 26214400)
                                 : ((size_t)OFF_H3C + 13107200);
        ws[off + (g & 63)] = 0;
    } else if (idx < TOTW + 3 * GUARD + H5N) {
        // zero the h5 atomic-accumulation scratch
        ((float*)(ws + OFF_H5S))[idx - (TOTW + 3 * GUARD)] = 0.f;
    } else if (dt) {
        int c = idx - (TOTW + 3 * GUARD + H5N);
        if (c < XCONV_N) {
            const float4* s = (const float4*)xv + (size_t)c * 2;
            float4 a = s[0], b = s[1];
            u16x8 o;
            o[0] = f2bf(a.x); o[1] = f2bf(a.y); o[2] = f2bf(a.z); o[3] = f2bf(a.w);
            o[4] = f2bf(b.x); o[5] = f2bf(b.y); o[6] = f2bf(b.z); o[7] = f2bf(b.w);
            ((u16x8*)(ws + OFF_XC))[c] = o;
        }
    }
}

// ---------------- GEMM: C[M,N] = A @ Wp^T + b ------------------------------
// 128x128 tile, BK=64, 4 waves each 64x64, mfma 16x16x32 bf16, bf16 A.
// 4 blocks/CU (capacity 1024: L1 grid 2048 = 2 exact waves, L3 1024 = 1).
// FUSE: compute h5 partials (h4 slab x W5^T col-slice) into f32 atomic scratch.
template <bool RELU, bool FUSE>
__global__ __launch_bounds__(256, 4) void gemm_bt(
    const int* __restrict__ flags,
    const u16* __restrict__ A0,        // mode-0 A source
    const u16* __restrict__ A1,        // mode-1 A source (ws bf16)
    int strideA, int Kpad, int NY,
    const u16* __restrict__ Wp,
    const void* __restrict__ bias, int N,
    void* __restrict__ dOut, size_t outOff,
    u16* __restrict__ Cc,
    const void* __restrict__ W5v, const void* __restrict__ m5v,
    float* __restrict__ scratch)
{
    const int mode = flags[0];
    const u16* __restrict__ A = mode ? A1 : A0;

    __shared__ __attribute__((aligned(16))) char sA[16384];
    __shared__ __attribute__((aligned(16))) char sB[16384];

    const int tid  = threadIdx.x;
    const int lane = tid & 63, wid = tid >> 6;
    const int wm = wid >> 1, wn = wid & 1;

    // XCD-chunked bijective remap (gridDim.x % 8 == 0 for all layers):
    // XCD k gets contiguous idx chunk; n = idx % NY varies fastest.
    const int per = gridDim.x >> 3;
    const int idx = (blockIdx.x & 7) * per + (blockIdx.x >> 3);
    const int bm0 = (idx / NY) * 128, bn0 = (idx % NY) * 128;

    const int q = lane >> 4, r15 = lane & 15, key = lane & 7;
    const int l3 = lane >> 3, l7 = lane & 7;
    const int kbx = (l7 ^ l3) << 3;     // XOR-swizzled source col (16B groups)

    const u16* gA = A  + (size_t)(bm0 + wid * 32 + l3) * (size_t)strideA + kbx;
    const u16* gB = Wp + (size_t)(bn0 + wid * 32 + l3) * (size_t)Kpad   + kbx;
    char* sAw = sA + wid * 4096;
    char* sBw = sB + wid * 4096;

    f32x4 acc[4][4];
#pragma unroll
    for (int i = 0; i < 4; ++i)
#pragma unroll
        for (int j = 0; j < 4; ++j) acc[i][j] = (f32x4){0.f, 0.f, 0.f, 0.f};

    for (int k0 = 0; k0 < Kpad; k0 += 64) {
        if (k0) __syncthreads();
#pragma unroll
        for (int t = 0; t < 4; ++t) {
            __builtin_amdgcn_global_load_lds(
                (const __attribute__((address_space(1))) void*)(gA + (size_t)t * 8 * strideA),
                (__attribute__((address_space(3))) void*)(sAw + t * 1024), 16, 0, 0);
            __builtin_amdgcn_global_load_lds(
                (const __attribute__((address_space(1))) void*)(gB + (size_t)t * 8 * Kpad),
                (__attribute__((address_space(3))) void*)(sBw + t * 1024), 16, 0, 0);
        }
        gA += 64; gB += 64;
        __syncthreads();

#pragma unroll
        for (int kk = 0; kk < 2; ++kk) {
            bf16x8 af[4], bfr[4];
#pragma unroll
            for (int mi = 0; mi < 4; ++mi)
                af[mi] = *(const bf16x8*)(sA + (wm * 64 + mi * 16 + r15) * 128 +
                                          (((kk * 4 + q) ^ key) << 4));
#pragma unroll
            for (int ni = 0; ni < 4; ++ni)
                bfr[ni] = *(const bf16x8*)(sB + (wn * 64 + ni * 16 + r15) * 128 +
                                           (((kk * 4 + q) ^ key) << 4));
#pragma unroll
            for (int mi = 0; mi < 4; ++mi)
#pragma unroll
                for (int ni = 0; ni < 4; ++ni)
                    acc[mi][ni] = __builtin_amdgcn_mfma_f32_16x16x32_bf16(
                        af[mi], bfr[ni], acc[mi][ni], 0, 0, 0);
        }
    }

    // FUSE: stage block's 6x128 masked W5 column-slice into (reused) sA
    float* w5s = (float*)sA;
    if constexpr (FUSE) {
        const int mwid = flags[1];
        __syncthreads();                 // all waves done reading sA
        for (int i = tid; i < 768; i += 256) {
            int j = i >> 7, c = i & 127, col = bn0 + c;
            float wv = 0.f;
            if (col < 600 && readM(m5v, j * 600 + col, mwid))
                wv = mode ? ((const float*)W5v)[j * 600 + col]
                          : b2f(((const u16*)W5v)[j * 600 + col]);
            w5s[i] = wv;
        }
        __syncthreads();
    }

    // epilogue: C/D layout col=lane&15, row=(lane>>4)*4+reg  [m89/m91]
    float bv[4];
#pragma unroll
    for (int ni = 0; ni < 4; ++ni) {
        int col = bn0 + wn * 64 + ni * 16 + r15;
        bv[ni] = (col < N) ? (mode ? ((const float*)bias)[col] : b2f(((const u16*)bias)[col]))
                           : 0.f;
    }
    float wreg[6][4];
    if constexpr (FUSE) {
#pragma unroll
        for (int j = 0; j < 6; ++j)
#pragma unroll
            for (int ni = 0; ni < 4; ++ni)
                wreg[j][ni] = w5s[j * 128 + wn * 64 + ni * 16 + r15];
    }

    float* out32 = (float*)dOut + outOff;
    u16*   out16 = (u16*)dOut + outOff;
#pragma unroll
    for (int mi = 0; mi < 4; ++mi) {
#pragma unroll
        for (int rr = 0; rr < 4; ++rr) {
            int row = bm0 + wm * 64 + mi * 16 + q * 4 + rr;
            float vv[4];
#pragma unroll
            for (int ni = 0; ni < 4; ++ni) {
                float v = acc[mi][ni][rr] + bv[ni];
                if (RELU) v = v > 0.f ? v : 0.f;
                vv[ni] = v;
                int col = bn0 + wn * 64 + ni * 16 + r15;
                if (col < N) {
                    size_t o = (size_t)row * N + col;
                    if (Cc) Cc[o] = f2bf(v);           // bf16 activation for next layer
                    if (mode) out32[o] = v;            // f32 output
                    else      out16[o] = f2bf(v);      // bf16 output
                }
            }
            if constexpr (FUSE) {
#pragma unroll
                for (int j = 0; j < 6; ++j) {
                    float p = vv[0] * wreg[j][0] + vv[1] * wreg[j][1] +
                              vv[2] * wreg[j][2] + vv[3] * wreg[j][3];
                    p += __shfl_xor(p, 1, 64);
                    p += __shfl_xor(p, 2, 64);
                    p += __shfl_xor(p, 4, 64);
                    p += __shfl_xor(p, 8, 64);
                    if (r15 == 0) atomicAdd(&scratch[(size_t)row * 6 + j], p);
                }
            }
        }
    }
}

// ---------------- finalize: h5 = scratch + b5, write both output slots -----
__global__ void finalize5(const int* __restrict__ flags,
                          const float* __restrict__ scratch,
                          const void* __restrict__ b5v, void* __restrict__ dOut)
{
    const int mode = flags[0];
    int idx = blockIdx.x * 256 + threadIdx.x;   // < 196608 exact
    int j = idx % 6;
    float v = scratch[idx] +
              (mode ? ((const float*)b5v)[j] : b2f(((const u16*)b5v)[j]));
    if (mode) {
        ((float*)dOut)[idx] = v;
        ((float*)dOut)[91947008 + idx] = v;
    } else {
        u16 b = f2bf(v);
        ((u16*)dOut)[idx] = b;
        ((u16*)dOut)[91947008 + idx] = b;
    }
}

// ---------------- launch ---------------------------------------------------
extern "C" void kernel_launch(void* const* d_in, const int* in_sizes, int n_in,
                              void* d_out, int out_size, void* d_ws, size_t ws_size,
                              hipStream_t stream) {
    int* flags = (int*)d_ws;
    u16* wsW   = (u16*)d_ws + WS_OFF;
    float* h5s = (float*)(wsW + OFF_H5S);

    detect_kernel<<<1, 64, 0, stream>>>(flags, (const u32*)d_in[0], (const u32*)d_in[3]);
    // weights + guards + h5-scratch zero + x->bf16
    // threads = TOTW + 192 + H5N + XCONV_N = 7069888 -> 27617 blocks
    prep_weights<<<27617, 256, 0, stream>>>(flags, wsW,
                                            d_in[1], d_in[3], d_in[4], d_in[6],
                                            d_in[7], d_in[9], d_in[10], d_in[12],
                                            d_in[0]);

    // d_out element offsets: h5a=0, h1=196608, h2=32964608, h3=59179008,
    // h4=72286208, h5b=91947008 (element-indexed, dtype per mode)
    // L1: M=32768 K=1024 N=1000 (NY=8)
    gemm_bt<true, false><<<2048, 256, 0, stream>>>(flags, (const u16*)d_in[0], wsW + OFF_XC,
                                                   1024, 1024, 8, wsW + OFF_W1, d_in[2], 1000,
                                                   d_out, 196608, wsW + OFF_H1C,
                                                   nullptr, nullptr, nullptr);
    // L2: K 1000 -> 1024 (zero-padded W cols absorb row overrun), N=800 (NY=7)
    gemm_bt<true, false><<<1792, 256, 0, stream>>>(flags, wsW + OFF_H1C, wsW + OFF_H1C,
                                                   1000, 1024, 7, wsW + OFF_W2, d_in[5], 800,
                                                   d_out, 32964608, wsW + OFF_H2C,
                                                   nullptr, nullptr, nullptr);
    // L3: K 800 -> 832, N=400 (NY=4)
    gemm_bt<true, false><<<1024, 256, 0, stream>>>(flags, wsW + OFF_H2C, wsW + OFF_H2C,
                                                   800, 832, 4, wsW + OFF_W3, d_in[8], 400,
                                                   d_out, 59179008, wsW + OFF_H3C,
                                                   nullptr, nullptr, nullptr);
    // L4: K 400 -> 448, N=600 (NY=5), no relu; h5 partials fused via atomics
    gemm_bt<false, true><<<1280, 256, 0, stream>>>(flags, wsW + OFF_H3C, wsW + OFF_H3C,
                                                   400, 448, 5, wsW + OFF_W4, d_in[11], 600,
                                                   d_out, 72286208, (u16*)nullptr,
                                                   d_in[13], d_in[15], h5s);
    // h5 = scratch + b5 -> both output slots
    finalize5<<<768, 256, 0, stream>>>(flags, h5s, d_in[14], d_out);
}

// Round 3
// 812.887 us; speedup vs baseline: 1.1269x; 1.1269x over previous
//
#include <hip/hip_runtime.h>
#include <stdint.h>

using u8  = unsigned char;
using u16 = unsigned short;
using u32 = unsigned int;

typedef __bf16 bf16x8 __attribute__((ext_vector_type(8)));
typedef float  f32x4  __attribute__((ext_vector_type(4)));
typedef u16    u16x8  __attribute__((ext_vector_type(8)));

#define AS1 __attribute__((address_space(1)))
#define AS3 __attribute__((address_space(3)))

__device__ __forceinline__ float b2f(u16 u) {
    union { u32 i; float f; } v; v.i = ((u32)u) << 16; return v.f;
}
__device__ __forceinline__ u16 f2bf(float f) {
    union { float f; u32 i; } v; v.f = f;
    u32 u = v.i;
    return (u16)((u + 0x7FFFu + ((u >> 16) & 1u)) >> 16);
}

// ws layout (u16 elements, relative to wsW = (u16*)d_ws + WS_OFF):
//   [OFF_W1..] masked zero-padded bf16 weights
//   [OFF_XC ] bf16 copy of x          32768x1024
//   [OFF_H1C] bf16 h1 + 64 guard      32768x1000
//   [OFF_H2C] bf16 h2 + 64 guard      32768x800
//   [OFF_H3C] bf16 h3 + 64 guard      32768x400
#define WS_OFF 256
#define OFF_W1 0
#define OFF_W2 1048576
#define OFF_W3 1966080
#define OFF_W4 2392064
#define PS1 1048576
#define PS2 917504
#define PS3 425984
#define PS4 286720
#define TOTW 2678784
#define GUARD 64
#define OFF_XC  2678784
#define OFF_H1C 36233216
#define OFF_H2C 69001280
#define OFF_H3C 95215744
#define XCONV_N 4194304   // 32768*1024/8

// ---------------- dtype / mask-width detection -----------------------------
__global__ void detect_kernel(int* __restrict__ flags,
                              const u32* __restrict__ xw,
                              const u32* __restrict__ mw) {
    const int lane = threadIdx.x;   // 64 threads
    int outl = 0;
#pragma unroll
    for (int i = 0; i < 4; ++i) {
        u32 u = xw[lane * 4 + i];
        u32 e = (u >> 7) & 0xFFu;              // exponent field of LOW u16 as bf16
        if (e < 90u || e > 140u) outl++;       // bf16 world: ~0 ; f32 world: ~80%
    }
#pragma unroll
    for (int off = 32; off; off >>= 1) outl += __shfl_down(outl, off, 64);

    u32 v0 = mw[lane], v1 = mw[64 + lane];
    bool w4 = (v0 == 0u || v0 == 1u || v0 == 0x3F800000u) &&
              (v1 == 0u || v1 == 1u || v1 == 0x3F800000u);
    auto okh = [](u32 h) { return h == 0u || h == 1u || h == 0x3F80u; };
    bool w2 = okh(v0 & 0xFFFFu) && okh(v0 >> 16) && okh(v1 & 0xFFFFu) && okh(v1 >> 16);
    int all4 = __all(w4 ? 1 : 0);
    int all2 = __all(w2 ? 1 : 0);
    if (lane == 0) {
        flags[0] = (outl > 64) ? 1 : 0;
        flags[1] = all4 ? 0 : (all2 ? 1 : 2);
    }
}

__device__ __forceinline__ bool readM(const void* m, int s, int mwid) {
    if (mwid == 0) return ((const u32*)m)[s] != 0u;
    if (mwid == 1) return ((const u16*)m)[s] != 0u;
    return ((const u8*)m)[s] != 0u;
}
__device__ __forceinline__ u16 readW(const void* W, int s, int dt) {
    if (dt) return f2bf(((const float*)W)[s]);
    return ((const u16*)W)[s];
}

// ------ weight prep + guards + (mode 1) x -> bf16 conversion ---------------
__global__ void prep_weights(const int* __restrict__ flags, u16* __restrict__ ws,
                             const void* __restrict__ W1, const void* __restrict__ m1,
                             const void* __restrict__ W2, const void* __restrict__ m2,
                             const void* __restrict__ W3, const void* __restrict__ m3,
                             const void* __restrict__ W4, const void* __restrict__ m4,
                             const void* __restrict__ xv)
{
    const int dt = flags[0], mwid = flags[1];
    int idx = blockIdx.x * 256 + threadIdx.x;
    if (idx < PS1) {
        int n = idx >> 10, k = idx & 1023;
        u16 v = 0;
        if (n < 1000) { int s = n * 1024 + k; if (readM(m1, s, mwid)) v = readW(W1, s, dt); }
        ws[idx] = v;
    } else if (idx < PS1 + PS2) {
        int j = idx - PS1; int n = j >> 10, k = j & 1023;
        u16 v = 0;
        if (n < 800 && k < 1000) { int s = n * 1000 + k; if (readM(m2, s, mwid)) v = readW(W2, s, dt); }
        ws[idx] = v;
    } else if (idx < PS1 + PS2 + PS3) {
        int j = idx - (PS1 + PS2); int n = j / 832, k = j - n * 832;
        u16 v = 0;
        if (n < 400 && k < 800) { int s = n * 800 + k; if (readM(m3, s, mwid)) v = readW(W3, s, dt); }
        ws[idx] = v;
    } else if (idx < TOTW) {
        int j = idx - (PS1 + PS2 + PS3); int n = j / 448, k = j - n * 448;
        u16 v = 0;
        if (n < 600 && k < 400) { int s = n * 400 + k; if (readM(m4, s, mwid)) v = readW(W4, s, dt); }
        ws[idx] = v;
    } else if (idx < TOTW + 3 * GUARD) {
        // zero guard bands after h1c/h2c/h3c (K-pad overrun of the LAST row
        // must read finite values; workspace poison may be NaN-patterned)
        int g = idx - TOTW;
        int zone = g >> 6;
        size_t off = (zone == 0) ? ((size_t)OFF_H1C + 32768000)
                   : (zone == 1) ? ((size_t)OFF_H2C + 26214400)
                                 : ((size_t)OFF_H3C + 13107200);
        ws[off + (g & 63)] = 0;
    } else if (dt) {
        int c = idx - (TOTW + 3 * GUARD);
        if (c < XCONV_N) {
            const float4* s = (const float4*)xv + (size_t)c * 2;
            float4 a = s[0], b = s[1];
            u16x8 o;
            o[0] = f2bf(a.x); o[1] = f2bf(a.y); o[2] = f2bf(a.z); o[3] = f2bf(a.w);
            o[4] = f2bf(b.x); o[5] = f2bf(b.y); o[6] = f2bf(b.z); o[7] = f2bf(b.w);
            ((u16x8*)(ws + OFF_XC))[c] = o;
        }
    }
}

// ---------------- 256x256 pipelined GEMM: C = A @ Wp^T + b -----------------
// BM=BN=256, BK=64 (2 K-halves of 32), 512 threads = 8 waves (2M x 4N),
// per-wave output 128x64, acc[8][4] f32x4. LDS 128 KiB:
//   A: [2 buf][2 half][256 rows][32 k] bf16 (16 KiB/half), B: same at +64 KiB.
// Per phase (t,kk): stage (t+1,kk) -> counted vmcnt(8) -> barrier ->
//   12x ds_read_b128 -> 32x MFMA (setprio). vmcnt never drains mid-loop.
// Swizzle: 16B block col c ^= (r>>1)&3  (2 lanes/bank on ds_read = free);
// staged with inverse-swizzled GLOBAL source + linear LDS dest.
template <bool RELU>
__global__ __launch_bounds__(512, 2) void gemm256(
    const int* __restrict__ flags,
    const u16* __restrict__ A0,        // mode-0 A source
    const u16* __restrict__ A1,        // mode-1 A source (ws bf16)
    int strideA, int NT, int NY,
    const u16* __restrict__ Wp,        // padded weights, row stride = NT*64
    const void* __restrict__ bias, int N,
    void* __restrict__ dOut, size_t outOff,
    u16* __restrict__ Cc)
{
    const int mode = flags[0];
    const u16* __restrict__ A = mode ? A1 : A0;
    const int Kpad = NT * 64;

    __shared__ __attribute__((aligned(16))) char smem[131072];

    const int tid  = threadIdx.x;
    const int lane = tid & 63;
    const int wid  = tid >> 6;            // 0..7
    const int wm = wid >> 2, wn = wid & 3;
    const int q = lane >> 4, r15 = lane & 15;
    const int csq = q ^ ((r15 >> 1) & 3); // frag-read swizzled 16B block (row-period 4)

    // XCD-chunked bijective remap (gridDim.x % 8 == 0): n fastest in chunk.
    const int per = gridDim.x >> 3;
    const int idx = (blockIdx.x & 7) * per + (blockIdx.x >> 3);
    const int bm0 = (idx / NY) * 256, bn0 = (idx % NY) * 256;

    // staging geometry (constant per thread): 2 16B loads per operand-half
    int srA[2], scA[2];
#pragma unroll
    for (int l = 0; l < 2; ++l) {
        int m = l * 512 + tid;            // 0..1023
        int r = m >> 2, c = m & 3;
        srA[l] = r;
        scA[l] = (c ^ ((r >> 1) & 3)) * 8;   // u16 offset within 32-k half
    }

    f32x4 acc[8][4];
#pragma unroll
    for (int i = 0; i < 8; ++i)
#pragma unroll
        for (int j = 0; j < 4; ++j) acc[i][j] = (f32x4){0.f, 0.f, 0.f, 0.f};

    // ---- stage one (t, kk) half-pair (A + B), 4 global_load_lds ----
    auto STAGE = [&](int t, int kk) {
        const int kb = t * 64 + kk * 32;       // u16 k offset
        const int pb = t & 1;
        char* ldsA = smem + pb * 32768 + kk * 16384;
        char* ldsB = smem + 65536 + pb * 32768 + kk * 16384;
#pragma unroll
        for (int l = 0; l < 2; ++l) {
            const u16* src = A + (size_t)(bm0 + srA[l]) * (size_t)strideA + kb + scA[l];
            __builtin_amdgcn_global_load_lds((const AS1 void*)src,
                (AS3 void*)(ldsA + (l * 512 + tid) * 16), 16, 0, 0);
        }
#pragma unroll
        for (int l = 0; l < 2; ++l) {
            const u16* src = Wp + (size_t)(bn0 + srA[l]) * (size_t)Kpad + kb + scA[l];
            __builtin_amdgcn_global_load_lds((const AS1 void*)src,
                (AS3 void*)(ldsB + (l * 512 + tid) * 16), 16, 0, 0);
        }
    };

    // prologue: K-tile 0, both halves (8 loads in flight)
    STAGE(0, 0);
    STAGE(0, 1);

    for (int t = 0; t < NT; ++t) {
        const int pb = t & 1;
#pragma unroll
        for (int kk = 0; kk < 2; ++kk) {
            const bool st = (t + 1 < NT);
            if (st) STAGE(t + 1, kk);
            // counted wait: allow the 2 newest half-pairs (8 loads) to fly;
            // guarantees (t,kk)'s data (staged 2 phases ago) has landed.
            if (st)           asm volatile("s_waitcnt vmcnt(8)" ::: "memory");
            else if (kk == 0) asm volatile("s_waitcnt vmcnt(4)" ::: "memory");
            else              asm volatile("s_waitcnt vmcnt(0)" ::: "memory");
            __builtin_amdgcn_s_barrier();
            __builtin_amdgcn_sched_barrier(0);

            const char* Ab = smem + pb * 32768 + kk * 16384;
            const char* Bb = smem + 65536 + pb * 32768 + kk * 16384;
            bf16x8 af[8], bfr[4];
#pragma unroll
            for (int mi = 0; mi < 8; ++mi) {
                int r = wm * 128 + mi * 16 + r15;
                af[mi] = *(const bf16x8*)(Ab + r * 64 + csq * 16);
            }
#pragma unroll
            for (int ni = 0; ni < 4; ++ni) {
                int r = wn * 64 + ni * 16 + r15;
                bfr[ni] = *(const bf16x8*)(Bb + r * 64 + csq * 16);
            }
            __builtin_amdgcn_s_setprio(1);
#pragma unroll
            for (int mi = 0; mi < 8; ++mi)
#pragma unroll
                for (int ni = 0; ni < 4; ++ni)
                    acc[mi][ni] = __builtin_amdgcn_mfma_f32_16x16x32_bf16(
                        af[mi], bfr[ni], acc[mi][ni], 0, 0, 0);
            __builtin_amdgcn_s_setprio(0);
        }
    }

    // epilogue: C/D layout col=lane&15, row=(lane>>4)*4+reg  [m89/m91]
    float bv[4];
#pragma unroll
    for (int ni = 0; ni < 4; ++ni) {
        int col = bn0 + wn * 64 + ni * 16 + r15;
        bv[ni] = (col < N) ? (mode ? ((const float*)bias)[col] : b2f(((const u16*)bias)[col]))
                           : 0.f;
    }
    float* out32 = (float*)dOut + outOff;
    u16*   out16 = (u16*)dOut + outOff;
#pragma unroll
    for (int mi = 0; mi < 8; ++mi) {
#pragma unroll
        for (int ni = 0; ni < 4; ++ni) {
            int col = bn0 + wn * 64 + ni * 16 + r15;
            if (col < N) {
#pragma unroll
                for (int rr = 0; rr < 4; ++rr) {
                    int row = bm0 + wm * 128 + mi * 16 + q * 4 + rr;
                    float v = acc[mi][ni][rr] + bv[ni];
                    if (RELU) v = v > 0.f ? v : 0.f;
                    size_t o = (size_t)row * N + col;
                    if (Cc) Cc[o] = f2bf(v);           // bf16 activation for next layer
                    if (mode) out32[o] = v;            // f32 output
                    else      out16[o] = f2bf(v);      // bf16 output
                }
            }
        }
    }
}

// ---------------- layer 5: [32768,600] @ [6,600]^T + b, N=6 ---------------
// reads mode-native h4 from d_out (bit-exact with prior version)
__global__ void layer5(const int* __restrict__ flags, void* __restrict__ dOut,
                       const void* __restrict__ W5v, const void* __restrict__ b5v,
                       const void* __restrict__ m5v)
{
    const int mode = flags[0], mwid = flags[1];
    __shared__ float w[6 * 600];
    __shared__ float bs[6];
    const int tid = threadIdx.x;
    for (int i = tid; i < 3600; i += 256)
        w[i] = readM(m5v, i, mwid)
                 ? (mode ? ((const float*)W5v)[i] : b2f(((const u16*)W5v)[i])) : 0.f;
    if (tid < 6)
        bs[tid] = mode ? ((const float*)b5v)[tid] : b2f(((const u16*)b5v)[tid]);
    __syncthreads();

    const int wid = tid >> 6, lane = tid & 63;
    const int row = blockIdx.x * 4 + wid;

    const float* h4f = (const float*)dOut + 72286208;
    const u16*   h4b = (const u16*)dOut + 72286208;

    float acc[6] = {0.f, 0.f, 0.f, 0.f, 0.f, 0.f};
    for (int p = lane; p < 300; p += 64) {
        float f0, f1;
        if (mode) {
            float2 hv = *(const float2*)(h4f + (size_t)row * 600 + 2 * p);
            f0 = hv.x; f1 = hv.y;
        } else {
            u32 u = *(const u32*)(h4b + (size_t)row * 600 + 2 * p);
            f0 = b2f((u16)(u & 0xffff)); f1 = b2f((u16)(u >> 16));
        }
        int k = 2 * p;
#pragma unroll
        for (int j = 0; j < 6; ++j) {
            float2 wv = *(const float2*)&w[j * 600 + k];
            acc[j] += f0 * wv.x + f1 * wv.y;
        }
    }
#pragma unroll
    for (int j = 0; j < 6; ++j)
#pragma unroll
        for (int off = 32; off > 0; off >>= 1)
            acc[j] += __shfl_down(acc[j], off, 64);

    if (lane == 0) {
#pragma unroll
        for (int j = 0; j < 6; ++j) {
            float v = acc[j] + bs[j];
            size_t o0 = (size_t)row * 6 + j;
            if (mode) {
                ((float*)dOut)[o0] = v;
                ((float*)dOut)[91947008 + o0] = v;
            } else {
                u16 b = f2bf(v);
                ((u16*)dOut)[o0] = b;
                ((u16*)dOut)[91947008 + o0] = b;
            }
        }
    }
}

// ---------------- launch ---------------------------------------------------
extern "C" void kernel_launch(void* const* d_in, const int* in_sizes, int n_in,
                              void* d_out, int out_size, void* d_ws, size_t ws_size,
                              hipStream_t stream) {
    int* flags = (int*)d_ws;
    u16* wsW   = (u16*)d_ws + WS_OFF;

    detect_kernel<<<1, 64, 0, stream>>>(flags, (const u32*)d_in[0], (const u32*)d_in[3]);
    // weights + guards + x->bf16 : (TOTW + 192 + XCONV_N) threads -> 26849 blocks
    prep_weights<<<26849, 256, 0, stream>>>(flags, wsW,
                                            d_in[1], d_in[3], d_in[4], d_in[6],
                                            d_in[7], d_in[9], d_in[10], d_in[12],
                                            d_in[0]);

    // d_out element offsets: h5a=0, h1=196608, h2=32964608, h3=59179008,
    // h4=72286208, h5b=91947008 (element-indexed, dtype per mode)
    // L1: M=32768 K=1024(NT=16) N=1000 (NY=4 -> 128x4 = 512 blocks, 2 exact waves)
    gemm256<true><<<512, 512, 0, stream>>>(flags, (const u16*)d_in[0], wsW + OFF_XC,
                                           1024, 16, 4, wsW + OFF_W1, d_in[2], 1000,
                                           d_out, 196608, wsW + OFF_H1C);
    // L2: K 1000 -> 1024 (zero-padded W cols absorb A row-spill), N=800 (NY=4)
    //     B rows 896..1023 over-read into W3 region (finite, cols>=N discarded)
    gemm256<true><<<512, 512, 0, stream>>>(flags, wsW + OFF_H1C, wsW + OFF_H1C,
                                           1000, 16, 4, wsW + OFF_W2, d_in[5], 800,
                                           d_out, 32964608, wsW + OFF_H2C);
    // L3: K 800 -> 832 (NT=13), N=400 (NY=2 -> 256 blocks, 1 exact wave)
    gemm256<true><<<256, 512, 0, stream>>>(flags, wsW + OFF_H2C, wsW + OFF_H2C,
                                           800, 13, 2, wsW + OFF_W3, d_in[8], 400,
                                           d_out, 59179008, wsW + OFF_H3C);
    // L4: K 400 -> 448 (NT=7), N=600 (NY=3 -> 384 blocks), no relu, no ws copy
    //     B rows 640..767 over-read into XC region (finite in mode1; mode0
    //     poison only reaches discarded cols>=600 accumulators)
    gemm256<false><<<384, 512, 0, stream>>>(flags, wsW + OFF_H3C, wsW + OFF_H3C,
                                            400, 7, 3, wsW + OFF_W4, d_in[11], 600,
                                            d_out, 72286208, (u16*)nullptr);
    // L5
    layer5<<<8192, 256, 0, stream>>>(flags, d_out, d_in[13], d_in[14], d_in[15]);
}